// Round 4
// baseline (310.417 us; speedup 1.0000x reference)
//
#include <hip/hip_runtime.h>
#include <math.h>

#define B_ 16384
#define NP 6

// smem float layout (peak 12800 floats = 51.2 KB)
#define A_OFF   0        // ph1 A: 64 rows x stride 65 = 4160
#define W1_OFF  4160     // ph1 W: 64 x 132 = 8448 -> 12608
#define X1_OFF  0        // X1: 64 x 100 = 6400 (after ph1)
#define W2_OFF  6400     // W2 chunk: 32 x 96 = 3072 -> 9472
#define X2_OFF  6400     // X2: 64 x 100 -> 12800 (after W2 done)
#define W3_OFF  0        // ph3 W panel: 96 x 64 = 6144
#define SMEMF   12800

__device__ __forceinline__ float gelu_f(float x) {
    return 0.5f * x * (1.0f + erff(x * 0.7071067811865476f));
}

// ---------------- kernel 1: counts + compacted lists + needs bitmap ----------------
__global__ __launch_bounds__(256) void k_count(
    const int* __restrict__ mask, int* __restrict__ counts,
    int* __restrict__ lists, unsigned long long* __restrict__ nb)
{
    int p   = blockIdx.x >> 3;
    int seg = blockIdx.x & 7;
    int src = p >> 1;                        // 0,0,1,1,2,2
    int tgt = (0x102021 >> (p * 4)) & 0xF;   // 1,2,0,2,0,1
    int t = threadIdx.x;
    int lane = t & 63;
    for (int it = 0; it < 8; ++it) {
        int b = seg * 2048 + it * 256 + t;
        int needs = (mask[b * 3 + src] != 0) && (mask[b * 3 + tgt] == 0);
        unsigned long long bal = __ballot(needs);
        int total = __popcll(bal);
        int base = 0;
        if (lane == 0) {
            nb[p * 256 + (b >> 6)] = bal;
            if (total) base = atomicAdd(&counts[p], total);
        }
        base = __shfl(base, 0, 64);
        if (needs) {
            int prefix = __popcll(bal & ((1ull << lane) - 1ull));
            lists[p * B_ + base + prefix] = b;
        }
    }
}

// ---------------- kernel 2: fused MLP + overlapped zero-fill ----------------
__global__ __launch_bounds__(256, 3) void k_main(
    const float* __restrict__ mus, const float* __restrict__ logvars,
    const float* __restrict__ hw1, const float* __restrict__ hb1,
    const float* __restrict__ hg1, const float* __restrict__ hbe1,
    const float* __restrict__ hw2, const float* __restrict__ hb2,
    const float* __restrict__ hg2, const float* __restrict__ hbe2,
    const float* __restrict__ hw3, const float* __restrict__ hb3,
    const float* __restrict__ gw1, const float* __restrict__ gb1,
    const float* __restrict__ gg1, const float* __restrict__ gbe1,
    const float* __restrict__ gw2, const float* __restrict__ gb2,
    const int* __restrict__ counts, const int* __restrict__ lists,
    const unsigned long long* __restrict__ nb,
    float* __restrict__ out0, float* __restrict__ out1, float* __restrict__ out2)
{
    int p = blockIdx.x >> 6;
    int s = blockIdx.x & 63;
    int t = threadIdx.x;
    int lane = t & 63, wave = t >> 6;
    int tx = t & 15, ty = t >> 4;

    __shared__ int   s_rows[64];
    __shared__ float smem[SMEMF];

    // -------- fire-and-forget zero-fill of dead rows in static slice s --------
    {
        unsigned long long nbv = nb[p * 256 + s * 4 + wave];
        size_t rowbase = ((size_t)p * B_ + s * 256 + wave * 64) * 256;
        float4 z = make_float4(0.f, 0.f, 0.f, 0.f);
        for (int r = 0; r < 64; ++r) {
            if (!((nbv >> r) & 1ull)) {
                *(float4*)(out0 + rowbase + (size_t)r * 256 + lane * 4) = z;
                *(float4*)(out1 + rowbase + (size_t)r * 256 + lane * 4) = z;
            }
        }
        int b2 = s * 256 + t;
        unsigned long long nb2 = nb[p * 256 + (b2 >> 6)];
        if (!((nb2 >> (b2 & 63)) & 1ull)) out2[p * B_ + b2] = 0.f;
    }

    int cnt = counts[p];
    const float* Ab  = mus     + (size_t)(p >> 1) * B_ * 256;
    const float* Lb  = logvars + (size_t)(p >> 1) * B_ * 256;
    const float* w1p = hw1 + (size_t)p * 512 * 96;
    const float* g1p = gw1 + (size_t)p * 512 * 32;
    const float* w2p = hw2 + (size_t)p * 96 * 96;
    const float* w3p = hw3 + (size_t)p * 96 * 512;

    for (int start = s * 64; start < cnt; start += 4096) {
        int nr = min(64, cnt - start);
        __syncthreads();
        if (t < 64) s_rows[t] = lists[p * B_ + start + min(t, nr - 1)];
        __syncthreads();

        // ============ phase 1: acc[4][8] = h(64x512) @ [hw1|gw1](512x128) ============
        float acc[4][8];
#pragma unroll
        for (int m = 0; m < 4; ++m)
#pragma unroll
            for (int n = 0; n < 8; ++n) acc[m][n] = 0.f;

        int ar = t >> 2, akc = t & 3;
        for (int kt = 0; kt < 8; ++kt) {
            const float* srcb = (kt < 4) ? Ab : Lb;
            int koff = (kt & 3) * 64;
            if (kt) __syncthreads();
            {   // A tile 64x64, row-major stride 65, scalar LDS writes (bank-clean)
                const float* ga = srcb + (size_t)s_rows[ar] * 256 + koff + akc * 16;
                float* la = smem + A_OFF + ar * 65 + akc * 16;
#pragma unroll
                for (int j = 0; j < 4; ++j) {
                    float4 v = *(const float4*)(ga + 4 * j);
                    la[4 * j + 0] = v.x; la[4 * j + 1] = v.y;
                    la[4 * j + 2] = v.z; la[4 * j + 3] = v.w;
                }
            }
            {   // W tile 64x(96|32), stride 132
                int wk = t >> 2;
                const float* gw = w1p + (size_t)(kt * 64 + wk) * 96;
                float* lw = smem + W1_OFF + wk * 132;
#pragma unroll
                for (int j = 0; j < 6; ++j) {
                    int c4 = (t & 3) * 6 + j;
                    *(float4*)(lw + 4 * c4) = *(const float4*)(gw + 4 * c4);
                }
                const float* gg = g1p + (size_t)(kt * 64 + wk) * 32;
#pragma unroll
                for (int j = 0; j < 2; ++j) {
                    int c4 = (t & 3) * 2 + j;
                    *(float4*)(lw + 96 + 4 * c4) = *(const float4*)(gg + 4 * c4);
                }
            }
            __syncthreads();

            const float* As = smem + A_OFF + 4 * ty * 65;
            const float* Ws = smem + W1_OFF + 4 * tx;
#pragma unroll 4
            for (int kk = 0; kk < 64; ++kk) {
                float a0 = As[kk], a1 = As[65 + kk], a2 = As[130 + kk], a3 = As[195 + kk];
                float4 wl = *(const float4*)(Ws + kk * 132);
                float4 wh = *(const float4*)(Ws + kk * 132 + 64);
                float wv[8] = {wl.x, wl.y, wl.z, wl.w, wh.x, wh.y, wh.z, wh.w};
#pragma unroll
                for (int n = 0; n < 8; ++n) {
                    acc[0][n] = fmaf(a0, wv[n], acc[0][n]);
                    acc[1][n] = fmaf(a1, wv[n], acc[1][n]);
                    acc[2][n] = fmaf(a2, wv[n], acc[2][n]);
                    acc[3][n] = fmaf(a3, wv[n], acc[3][n]);
                }
            }
        }
        __syncthreads();

        // ====== LN1 + gelu in registers; cols {4tx..+3} (h) and {64+4tx..+3} (h if tx<8 else gate) ======
#pragma unroll
        for (int m = 0; m < 4; ++m) {
            int r = 4 * ty + m;
            float v[8];
#pragma unroll
            for (int n = 0; n < 4; ++n) v[n] = acc[m][n] + hb1[p * 96 + 4 * tx + n];
            if (tx < 8) {
#pragma unroll
                for (int n = 0; n < 4; ++n) v[4 + n] = acc[m][4 + n] + hb1[p * 96 + 64 + 4 * tx + n];
            } else {
#pragma unroll
                for (int n = 0; n < 4; ++n) v[4 + n] = acc[m][4 + n] + gb1[p * 32 + 4 * (tx - 8) + n];
            }
            float hs = v[0] + v[1] + v[2] + v[3] + ((tx < 8) ? v[4] + v[5] + v[6] + v[7] : 0.f);
#pragma unroll
            for (int mk = 8; mk; mk >>= 1) hs += __shfl_xor(hs, mk, 16);
            float mean = hs * (1.f / 96.f);
            float sq = 0.f;
#pragma unroll
            for (int n = 0; n < 4; ++n) { float d = v[n] - mean; sq += d * d; }
            if (tx < 8) {
#pragma unroll
                for (int n = 0; n < 4; ++n) { float d = v[4 + n] - mean; sq += d * d; }
            }
#pragma unroll
            for (int mk = 8; mk; mk >>= 1) sq += __shfl_xor(sq, mk, 16);
            float rs = rsqrtf(sq * (1.f / 96.f) + 1e-5f);

            {   // lo 4 cols always h
                float4 xo;
                int c = 4 * tx;
                xo.x = gelu_f((v[0] - mean) * rs * hg1[p * 96 + c + 0] + hbe1[p * 96 + c + 0]);
                xo.y = gelu_f((v[1] - mean) * rs * hg1[p * 96 + c + 1] + hbe1[p * 96 + c + 1]);
                xo.z = gelu_f((v[2] - mean) * rs * hg1[p * 96 + c + 2] + hbe1[p * 96 + c + 2]);
                xo.w = gelu_f((v[3] - mean) * rs * hg1[p * 96 + c + 3] + hbe1[p * 96 + c + 3]);
                *(float4*)(smem + X1_OFF + r * 100 + c) = xo;
            }
            if (tx < 8) {
                float4 xo;
                int c = 64 + 4 * tx;
                xo.x = gelu_f((v[4] - mean) * rs * hg1[p * 96 + c + 0] + hbe1[p * 96 + c + 0]);
                xo.y = gelu_f((v[5] - mean) * rs * hg1[p * 96 + c + 1] + hbe1[p * 96 + c + 1]);
                xo.z = gelu_f((v[6] - mean) * rs * hg1[p * 96 + c + 2] + hbe1[p * 96 + c + 2]);
                xo.w = gelu_f((v[7] - mean) * rs * hg1[p * 96 + c + 3] + hbe1[p * 96 + c + 3]);
                *(float4*)(smem + X1_OFF + r * 100 + c) = xo;
            } else {
                // gate branch: LN over 32 cols held by lanes tx=8..15
                float gs = v[4] + v[5] + v[6] + v[7];
                gs += __shfl_xor(gs, 1, 16); gs += __shfl_xor(gs, 2, 16); gs += __shfl_xor(gs, 4, 16);
                float mg = gs * (1.f / 32.f);
                float gq = 0.f;
#pragma unroll
                for (int n = 0; n < 4; ++n) { float d = v[4 + n] - mg; gq += d * d; }
                gq += __shfl_xor(gq, 1, 16); gq += __shfl_xor(gq, 2, 16); gq += __shfl_xor(gq, 4, 16);
                float rsg = rsqrtf(gq * (1.f / 32.f) + 1e-5f);
                float gv = 0.f;
#pragma unroll
                for (int n = 0; n < 4; ++n) {
                    int cg = 4 * (tx - 8) + n;
                    gv += gelu_f((v[4 + n] - mg) * rsg * gg1[p * 32 + cg] + gbe1[p * 32 + cg]) * gw2[p * 32 + cg];
                }
                gv += __shfl_xor(gv, 1, 16); gv += __shfl_xor(gv, 2, 16); gv += __shfl_xor(gv, 4, 16);
                if (tx == 8 && r < nr)
                    out2[p * B_ + s_rows[r]] = 1.f / (1.f + expf(-(gv + gb2[p])));
            }
        }
        __syncthreads();

        // ============ phase 2: acc2[4][6] = X1(64x96) @ hw2(96x96), cols {3tx, 48+3tx} ============
        float acc2[4][6];
#pragma unroll
        for (int m = 0; m < 4; ++m)
#pragma unroll
            for (int n = 0; n < 6; ++n) acc2[m][n] = 0.f;

        for (int c3 = 0; c3 < 3; ++c3) {
            if (c3) __syncthreads();
            {   // stage 32x96 W2 chunk
                int k = t >> 3;
                const float* gw = w2p + (size_t)(c3 * 32 + k) * 96;
                float* lw = smem + W2_OFF + k * 96;
#pragma unroll
                for (int j = 0; j < 3; ++j) {
                    int c4 = (t & 7) * 3 + j;
                    *(float4*)(lw + 4 * c4) = *(const float4*)(gw + 4 * c4);
                }
            }
            __syncthreads();
            const float* As = smem + X1_OFF + 4 * ty * 100 + c3 * 32;
            const float* Ws = smem + W2_OFF;
#pragma unroll 2
            for (int kk = 0; kk < 32; ++kk) {
                float a0 = As[kk], a1 = As[100 + kk], a2 = As[200 + kk], a3 = As[300 + kk];
                const float* wr = Ws + kk * 96;
                float wv[6] = {wr[3 * tx], wr[3 * tx + 1], wr[3 * tx + 2],
                               wr[48 + 3 * tx], wr[48 + 3 * tx + 1], wr[48 + 3 * tx + 2]};
#pragma unroll
                for (int n = 0; n < 6; ++n) {
                    acc2[0][n] = fmaf(a0, wv[n], acc2[0][n]);
                    acc2[1][n] = fmaf(a1, wv[n], acc2[1][n]);
                    acc2[2][n] = fmaf(a2, wv[n], acc2[2][n]);
                    acc2[3][n] = fmaf(a3, wv[n], acc2[3][n]);
                }
            }
        }
        __syncthreads();   // W2 region about to become X2

        // ====== LN2 + gelu -> X2 (all 96 cols are h) ======
#pragma unroll
        for (int m = 0; m < 4; ++m) {
            int r = 4 * ty + m;
            float v[6];
#pragma unroll
            for (int n = 0; n < 3; ++n) v[n] = acc2[m][n] + hb2[p * 96 + 3 * tx + n];
#pragma unroll
            for (int n = 0; n < 3; ++n) v[3 + n] = acc2[m][3 + n] + hb2[p * 96 + 48 + 3 * tx + n];
            float hs = v[0] + v[1] + v[2] + v[3] + v[4] + v[5];
#pragma unroll
            for (int mk = 8; mk; mk >>= 1) hs += __shfl_xor(hs, mk, 16);
            float mean = hs * (1.f / 96.f);
            float sq = 0.f;
#pragma unroll
            for (int n = 0; n < 6; ++n) { float d = v[n] - mean; sq += d * d; }
#pragma unroll
            for (int mk = 8; mk; mk >>= 1) sq += __shfl_xor(sq, mk, 16);
            float rs = rsqrtf(sq * (1.f / 96.f) + 1e-5f);
#pragma unroll
            for (int n = 0; n < 3; ++n) {
                int c = 3 * tx + n;
                smem[X2_OFF + r * 100 + c] = gelu_f((v[n] - mean) * rs * hg2[p * 96 + c] + hbe2[p * 96 + c]);
            }
#pragma unroll
            for (int n = 0; n < 3; ++n) {
                int c = 48 + 3 * tx + n;
                smem[X2_OFF + r * 100 + c] = gelu_f((v[3 + n] - mean) * rs * hg2[p * 96 + c] + hbe2[p * 96 + c]);
            }
        }
        __syncthreads();

        // ============ phase 3: out(64x512) = X2(64x96) @ hw3(96x512), 8 panels of 64 cols ============
        for (int cp = 0; cp < 8; ++cp) {
            if (cp) __syncthreads();
#pragma unroll
            for (int j = 0; j < 6; ++j) {   // stage 96x64 W3 panel, stride 64
                int idx = t + 256 * j;
                int row = idx >> 4, c4 = idx & 15;
                *(float4*)(smem + W3_OFF + row * 64 + 4 * c4) =
                    *(const float4*)(w3p + (size_t)row * 512 + cp * 64 + 4 * c4);
            }
            __syncthreads();

            float acc3[4][4];
#pragma unroll
            for (int m = 0; m < 4; ++m)
#pragma unroll
                for (int n = 0; n < 4; ++n) acc3[m][n] = 0.f;

            const float* As = smem + X2_OFF + 4 * ty * 100;
            const float* Ws = smem + W3_OFF + 4 * tx;
#pragma unroll 4
            for (int kk = 0; kk < 96; ++kk) {
                float a0 = As[kk], a1 = As[100 + kk], a2 = As[200 + kk], a3 = As[300 + kk];
                float4 w = *(const float4*)(Ws + kk * 64);
                acc3[0][0] = fmaf(a0, w.x, acc3[0][0]); acc3[1][0] = fmaf(a1, w.x, acc3[1][0]);
                acc3[2][0] = fmaf(a2, w.x, acc3[2][0]); acc3[3][0] = fmaf(a3, w.x, acc3[3][0]);
                acc3[0][1] = fmaf(a0, w.y, acc3[0][1]); acc3[1][1] = fmaf(a1, w.y, acc3[1][1]);
                acc3[2][1] = fmaf(a2, w.y, acc3[2][1]); acc3[3][1] = fmaf(a3, w.y, acc3[3][1]);
                acc3[0][2] = fmaf(a0, w.z, acc3[0][2]); acc3[1][2] = fmaf(a1, w.z, acc3[1][2]);
                acc3[2][2] = fmaf(a2, w.z, acc3[2][2]); acc3[3][2] = fmaf(a3, w.z, acc3[3][2]);
                acc3[0][3] = fmaf(a0, w.w, acc3[0][3]); acc3[1][3] = fmaf(a1, w.w, acc3[1][3]);
                acc3[2][3] = fmaf(a2, w.w, acc3[2][3]); acc3[3][3] = fmaf(a3, w.w, acc3[3][3]);
            }

            int c = cp * 64 + 4 * tx;
            float4 b4 = *(const float4*)(hb3 + p * 512 + c);
#pragma unroll
            for (int m = 0; m < 4; ++m) {
                int r = 4 * ty + m;
                if (r < nr) {
                    int b = s_rows[r];
                    size_t rb = ((size_t)(p * B_ + b)) * 256;
                    float o0 = acc3[m][0] + b4.x, o1 = acc3[m][1] + b4.y;
                    float o2 = acc3[m][2] + b4.z, o3 = acc3[m][3] + b4.w;
                    if (cp < 4) {
                        *(float4*)(out0 + rb + c) = make_float4(o0, o1, o2, o3);
                    } else {
                        o0 = fminf(fmaxf(o0, -6.f), 2.f); o1 = fminf(fmaxf(o1, -6.f), 2.f);
                        o2 = fminf(fmaxf(o2, -6.f), 2.f); o3 = fminf(fmaxf(o3, -6.f), 2.f);
                        *(float4*)(out1 + rb + (c - 256)) = make_float4(o0, o1, o2, o3);
                    }
                }
            }
        }
    }
}

extern "C" void kernel_launch(void* const* d_in, const int* in_sizes, int n_in,
                              void* d_out, int out_size, void* d_ws, size_t ws_size,
                              hipStream_t stream)
{
    (void)in_sizes; (void)n_in; (void)out_size; (void)ws_size;

    const float* mus     = (const float*)d_in[0];
    const float* logvars = (const float*)d_in[1];
    const int*   mask    = (const int*)d_in[2];   // numpy bool -> int32 per harness
    const float* hw1  = (const float*)d_in[3];
    const float* hb1  = (const float*)d_in[4];
    const float* hg1  = (const float*)d_in[5];
    const float* hbe1 = (const float*)d_in[6];
    const float* hw2  = (const float*)d_in[7];
    const float* hb2  = (const float*)d_in[8];
    const float* hg2  = (const float*)d_in[9];
    const float* hbe2 = (const float*)d_in[10];
    const float* hw3  = (const float*)d_in[11];
    const float* hb3  = (const float*)d_in[12];
    const float* gw1  = (const float*)d_in[13];
    const float* gb1  = (const float*)d_in[14];
    const float* gg1  = (const float*)d_in[15];
    const float* gbe1 = (const float*)d_in[16];
    const float* gw2  = (const float*)d_in[17];
    const float* gb2  = (const float*)d_in[18];

    float* out0 = (float*)d_out;
    float* out1 = out0 + (size_t)NP * B_ * 256;
    float* out2 = out1 + (size_t)NP * B_ * 256;

    int* counts = (int*)d_ws;                       // 16 ints
    int* lists  = counts + 16;                      // 6*16384 ints
    unsigned long long* nbm =
        (unsigned long long*)(lists + NP * B_);     // 6*256 u64

    hipMemsetAsync(d_ws, 0, 64, stream);
    k_count<<<dim3(NP * 8), dim3(256), 0, stream>>>(mask, counts, lists, nbm);
    k_main<<<dim3(NP * 64), dim3(256), 0, stream>>>(
        mus, logvars, hw1, hb1, hg1, hbe1, hw2, hb2, hg2, hbe2, hw3, hb3,
        gw1, gb1, gg1, gbe1, gw2, gb2, counts, lists, nbm, out0, out1, out2);
}

// Round 5
// 183.164 us; speedup vs baseline: 1.6948x; 1.6948x over previous
//
#include <hip/hip_runtime.h>
#include <math.h>

#define B_ 16384
#define NP 6

typedef short v8s __attribute__((ext_vector_type(8)));
typedef float v4f __attribute__((ext_vector_type(4)));

// LDS ushort offsets (total 18176 ushort = 36352 B)
#define A_O    0        // ph1 A tile   [32][72]  = 2304
#define W1_O   2304     // ph1 W tile   [128][72] = 9216 -> 11520
#define X1_O   11520    // X1           [32][104] = 3328 -> 14848
#define W2_O   0        // W2T          [96][104] = 9984 (after ph1, overlaps A/W1)
#define X2_O   14848    // X2           [32][104] = 3328 -> 18176
#define W3_O   0        // W3T panel    [128][104]= 13312 (after ph2)
#define SM_SH  18176

__device__ __forceinline__ float gelu_f(float x) {
    return 0.5f * x * (1.0f + erff(x * 0.7071067811865476f));
}

__device__ __forceinline__ unsigned short f2bf(float f) {
    union { float f; unsigned u; } x; x.f = f;
    unsigned r = x.u + 0x7FFFu + ((x.u >> 16) & 1u);
    return (unsigned short)(r >> 16);
}

// ---------------- kernel 0: weights -> bf16, transposed [col][k] ----------------
__global__ __launch_bounds__(256) void k_prep(
    const float* __restrict__ hw1, const float* __restrict__ gw1,
    const float* __restrict__ hw2, const float* __restrict__ hw3,
    unsigned short* __restrict__ w1t, unsigned short* __restrict__ w2t,
    unsigned short* __restrict__ w3t)
{
    const int T1 = NP * 65536, T2 = NP * 9216, T3 = NP * 49152;
    for (int i = blockIdx.x * 256 + threadIdx.x; i < T1 + T2 + T3; i += gridDim.x * 256) {
        if (i < T1) {
            int p = i >> 16, rem = i & 65535, c = rem >> 9, k = rem & 511;
            float v = (c < 96) ? hw1[p * 49152 + k * 96 + c] : gw1[p * 16384 + k * 32 + (c - 96)];
            w1t[i] = f2bf(v);
        } else if (i < T1 + T2) {
            int j = i - T1, p = j / 9216, r2 = j % 9216, c = r2 / 96, k = r2 % 96;
            w2t[j] = f2bf(hw2[p * 9216 + k * 96 + c]);
        } else {
            int j = i - T1 - T2, p = j / 49152, r3 = j % 49152, c = r3 / 96, k = r3 % 96;
            w3t[j] = f2bf(hw3[p * 49152 + k * 512 + c]);
        }
    }
}

// ---------------- kernel 1: needs + compaction + zero-fill dead rows ----------------
__global__ __launch_bounds__(256) void k_mask(
    const int* __restrict__ mask,
    float* __restrict__ out0, float* __restrict__ out1, float* __restrict__ out2,
    int* __restrict__ counts, int* __restrict__ lists)
{
    int p    = blockIdx.x >> 8;
    int tile = blockIdx.x & 255;
    int row0 = tile * 64;
    int t    = threadIdx.x;
    int src  = p >> 1;                       // 0,0,1,1,2,2
    int tgt  = (0x102021 >> (p * 4)) & 0xF;  // 1,2,0,2,0,1

    __shared__ int s_needs[64];
    if (t < 64) {
        int b  = row0 + t;
        int needs = (mask[b * 3 + src] != 0) && (mask[b * 3 + tgt] == 0);
        s_needs[t] = needs;
        unsigned long long bal = __ballot(needs);
        int total = __popcll(bal);
        int base = 0;
        if (t == 0 && total) base = atomicAdd(&counts[p], total);
        base = __shfl(base, 0, 64);
        if (needs) {
            int prefix = __popcll(bal & ((1ull << t) - 1ull));
            lists[p * B_ + base + prefix] = b;
        }
    }
    __syncthreads();

    int wave = t >> 6, lane = t & 63;
    float4 z = make_float4(0.f, 0.f, 0.f, 0.f);
    for (int r = wave; r < 64; r += 4) {
        if (!s_needs[r]) {
            size_t rowoff = ((size_t)(p * B_ + row0 + r)) * 256 + lane * 4;
            *(float4*)(out0 + rowoff) = z;
            *(float4*)(out1 + rowoff) = z;
        }
    }
    if (t < 64 && !s_needs[t]) out2[p * B_ + row0 + t] = 0.f;
}

// ---------------- kernel 2: fused MFMA MLP over compacted rows ----------------
__global__ __launch_bounds__(128, 2) void k_main(
    const float* __restrict__ mus, const float* __restrict__ logvars,
    const unsigned short* __restrict__ w1t, const unsigned short* __restrict__ w2t,
    const unsigned short* __restrict__ w3t,
    const float* __restrict__ hb1, const float* __restrict__ hg1, const float* __restrict__ hbe1,
    const float* __restrict__ hb2, const float* __restrict__ hg2, const float* __restrict__ hbe2,
    const float* __restrict__ hb3,
    const float* __restrict__ gb1, const float* __restrict__ gg1, const float* __restrict__ gbe1,
    const float* __restrict__ gw2, const float* __restrict__ gb2,
    const int* __restrict__ counts, const int* __restrict__ lists,
    float* __restrict__ out0, float* __restrict__ out1, float* __restrict__ out2)
{
    int p    = blockIdx.x >> 7;
    int tile = blockIdx.x & 127;
    int cnt  = counts[p];

    int t    = threadIdx.x;
    int w    = t >> 6;          // wave 0/1 -> rows 16w..16w+15
    int lane = t & 63;
    int g    = lane >> 4;       // k-group 0..3
    int q    = lane & 15;       // col-in-tile / row-in-frag

    __shared__ __align__(16) unsigned short sm[SM_SH];
    __shared__ int s_rows[32];

    const float* Ab = mus     + (size_t)(p >> 1) * B_ * 256;
    const float* Lb = logvars + (size_t)(p >> 1) * B_ * 256;
    const unsigned short* w1p = w1t + (size_t)p * 65536;
    const unsigned short* w2p = w2t + (size_t)p * 9216;
    const unsigned short* w3p = w3t + (size_t)p * 49152;
    float gb2p = gb2[p];

    for (int start = tile * 32; start < cnt; start += 128 * 32) {
        int nr = min(32, cnt - start);
        __syncthreads();
        if (t < 32) s_rows[t] = lists[p * B_ + start + min(t, nr - 1)];
        __syncthreads();

        // ============ phase 1: acc1[8] (16 rows x 128 cols per wave), K=512 ============
        v4f acc1[8];
#pragma unroll
        for (int n = 0; n < 8; ++n) acc1[n] = (v4f){0.f, 0.f, 0.f, 0.f};

        int arow = t >> 2, aseg = t & 3;
        for (int kt = 0; kt < 8; ++kt) {
            const float* srcb = (kt < 4) ? Ab : Lb;
            int koff = (kt & 3) * 64;
            if (kt) __syncthreads();
            {   // A tile 32x64 f32 -> bf16, stride 72
                const float* ga = srcb + (size_t)s_rows[arow] * 256 + koff + aseg * 16;
                v8s v0, v1;
#pragma unroll
                for (int jj = 0; jj < 2; ++jj) {
                    float4 f0 = ((const float4*)ga)[jj * 2];
                    float4 f1 = ((const float4*)ga)[jj * 2 + 1];
                    v8s vv;
                    vv[0] = (short)f2bf(f0.x); vv[1] = (short)f2bf(f0.y);
                    vv[2] = (short)f2bf(f0.z); vv[3] = (short)f2bf(f0.w);
                    vv[4] = (short)f2bf(f1.x); vv[5] = (short)f2bf(f1.y);
                    vv[6] = (short)f2bf(f1.z); vv[7] = (short)f2bf(f1.w);
                    if (jj == 0) v0 = vv; else v1 = vv;
                }
                unsigned short* la = sm + A_O + arow * 72 + aseg * 16;
                *(v8s*)la = v0;
                *(v8s*)(la + 8) = v1;
            }
            {   // W1T tile [128 cols][64 k], stride 72
                const unsigned short* gsrc = w1p + (size_t)t * 512 + kt * 64;
                unsigned short* ld = sm + W1_O + t * 72;
#pragma unroll
                for (int j = 0; j < 8; ++j)
                    *(v8s*)(ld + j * 8) = *(const v8s*)(gsrc + j * 8);
            }
            __syncthreads();

#pragma unroll
            for (int kit = 0; kit < 2; ++kit) {
                v8s a = *(const v8s*)(sm + A_O + (16 * w + q) * 72 + kit * 32 + g * 8);
#pragma unroll
                for (int n = 0; n < 8; ++n) {
                    v8s b = *(const v8s*)(sm + W1_O + (n * 16 + q) * 72 + kit * 32 + g * 8);
                    acc1[n] = __builtin_amdgcn_mfma_f32_16x16x32_bf16(a, b, acc1[n], 0, 0, 0);
                }
            }
        }

        // ====== LN1 + gelu (f32, 16-lane shuffles); gate branch fused ======
        {
            float vb[8][4];
#pragma unroll
            for (int n = 0; n < 8; ++n) {
                float bias = (n < 6) ? hb1[p * 96 + n * 16 + q] : gb1[p * 32 + (n - 6) * 16 + q];
#pragma unroll
                for (int j = 0; j < 4; ++j) vb[n][j] = acc1[n][j] + bias;
            }
            float mean[4], rs[4];
#pragma unroll
            for (int j = 0; j < 4; ++j) {
                float hs = vb[0][j] + vb[1][j] + vb[2][j] + vb[3][j] + vb[4][j] + vb[5][j];
                hs += __shfl_xor(hs, 1, 16); hs += __shfl_xor(hs, 2, 16);
                hs += __shfl_xor(hs, 4, 16); hs += __shfl_xor(hs, 8, 16);
                float mn = hs * (1.f / 96.f);
                float sq = 0.f;
#pragma unroll
                for (int n = 0; n < 6; ++n) { float d = vb[n][j] - mn; sq += d * d; }
                sq += __shfl_xor(sq, 1, 16); sq += __shfl_xor(sq, 2, 16);
                sq += __shfl_xor(sq, 4, 16); sq += __shfl_xor(sq, 8, 16);
                mean[j] = mn; rs[j] = rsqrtf(sq * (1.f / 96.f) + 1e-5f);
            }
#pragma unroll
            for (int n = 0; n < 6; ++n) {
                int c = n * 16 + q;
                float ga_ = hg1[p * 96 + c], be_ = hbe1[p * 96 + c];
#pragma unroll
                for (int j = 0; j < 4; ++j) {
                    float x = gelu_f((vb[n][j] - mean[j]) * rs[j] * ga_ + be_);
                    sm[X1_O + (16 * w + 4 * g + j) * 104 + c] = f2bf(x);
                }
            }
            // gate: 32 cols = frags n=6,7
            float g1a = gg1[p * 32 + q],      b1a = gbe1[p * 32 + q],      w2a = gw2[p * 32 + q];
            float g1b = gg1[p * 32 + 16 + q], b1b = gbe1[p * 32 + 16 + q], w2b = gw2[p * 32 + 16 + q];
#pragma unroll
            for (int j = 0; j < 4; ++j) {
                float s = vb[6][j] + vb[7][j];
                s += __shfl_xor(s, 1, 16); s += __shfl_xor(s, 2, 16);
                s += __shfl_xor(s, 4, 16); s += __shfl_xor(s, 8, 16);
                float mg = s * (1.f / 32.f);
                float d6 = vb[6][j] - mg, d7 = vb[7][j] - mg;
                float sq = d6 * d6 + d7 * d7;
                sq += __shfl_xor(sq, 1, 16); sq += __shfl_xor(sq, 2, 16);
                sq += __shfl_xor(sq, 4, 16); sq += __shfl_xor(sq, 8, 16);
                float rg = rsqrtf(sq * (1.f / 32.f) + 1e-5f);
                float gv = gelu_f(d6 * rg * g1a + b1a) * w2a + gelu_f(d7 * rg * g1b + b1b) * w2b;
                gv += __shfl_xor(gv, 1, 16); gv += __shfl_xor(gv, 2, 16);
                gv += __shfl_xor(gv, 4, 16); gv += __shfl_xor(gv, 8, 16);
                int r = 16 * w + 4 * g + j;
                if (q == 0 && r < nr)
                    out2[p * B_ + s_rows[r]] = 1.f / (1.f + expf(-(gv + gb2p)));
            }
        }

        __syncthreads();   // ph1 reads done; X1 written
        {   // stage W2T [96][104]
            if (t < 96) {
                const unsigned short* gsrc = w2p + (size_t)t * 96;
                unsigned short* ld = sm + W2_O + t * 104;
#pragma unroll
                for (int j = 0; j < 12; ++j)
                    *(v8s*)(ld + j * 8) = *(const v8s*)(gsrc + j * 8);
            }
        }
        __syncthreads();

        // ============ phase 2: acc2[6] = X1(16x96) @ W2(96x96) ============
        v4f acc2[6];
#pragma unroll
        for (int n = 0; n < 6; ++n) acc2[n] = (v4f){0.f, 0.f, 0.f, 0.f};
#pragma unroll
        for (int kit = 0; kit < 3; ++kit) {
            v8s a = *(const v8s*)(sm + X1_O + (16 * w + q) * 104 + kit * 32 + g * 8);
#pragma unroll
            for (int n = 0; n < 6; ++n) {
                v8s b = *(const v8s*)(sm + W2_O + (n * 16 + q) * 104 + kit * 32 + g * 8);
                acc2[n] = __builtin_amdgcn_mfma_f32_16x16x32_bf16(a, b, acc2[n], 0, 0, 0);
            }
        }

        // ====== LN2 + gelu -> X2 (bf16) ======
        {
            float vc[6][4];
#pragma unroll
            for (int n = 0; n < 6; ++n) {
                float bias = hb2[p * 96 + n * 16 + q];
#pragma unroll
                for (int j = 0; j < 4; ++j) vc[n][j] = acc2[n][j] + bias;
            }
            float mean[4], rs[4];
#pragma unroll
            for (int j = 0; j < 4; ++j) {
                float hs = vc[0][j] + vc[1][j] + vc[2][j] + vc[3][j] + vc[4][j] + vc[5][j];
                hs += __shfl_xor(hs, 1, 16); hs += __shfl_xor(hs, 2, 16);
                hs += __shfl_xor(hs, 4, 16); hs += __shfl_xor(hs, 8, 16);
                float mn = hs * (1.f / 96.f);
                float sq = 0.f;
#pragma unroll
                for (int n = 0; n < 6; ++n) { float d = vc[n][j] - mn; sq += d * d; }
                sq += __shfl_xor(sq, 1, 16); sq += __shfl_xor(sq, 2, 16);
                sq += __shfl_xor(sq, 4, 16); sq += __shfl_xor(sq, 8, 16);
                mean[j] = mn; rs[j] = rsqrtf(sq * (1.f / 96.f) + 1e-5f);
            }
#pragma unroll
            for (int n = 0; n < 6; ++n) {
                int c = n * 16 + q;
                float ga_ = hg2[p * 96 + c], be_ = hbe2[p * 96 + c];
#pragma unroll
                for (int j = 0; j < 4; ++j) {
                    float x = gelu_f((vc[n][j] - mean[j]) * rs[j] * ga_ + be_);
                    sm[X2_O + (16 * w + 4 * g + j) * 104 + c] = f2bf(x);
                }
            }
        }

        // ============ phase 3: out(32x512) = X2(32x96) @ W3(96x512), 4 panels ============
        for (int pc = 0; pc < 4; ++pc) {
            __syncthreads();
            {   // stage W3T panel [128 cols][96 k]
                const unsigned short* gsrc = w3p + (size_t)(pc * 128 + t) * 96;
                unsigned short* ld = sm + W3_O + t * 104;
#pragma unroll
                for (int j = 0; j < 12; ++j)
                    *(v8s*)(ld + j * 8) = *(const v8s*)(gsrc + j * 8);
            }
            __syncthreads();

            v4f acc3[8];
#pragma unroll
            for (int n = 0; n < 8; ++n) acc3[n] = (v4f){0.f, 0.f, 0.f, 0.f};
#pragma unroll
            for (int kit = 0; kit < 3; ++kit) {
                v8s a = *(const v8s*)(sm + X2_O + (16 * w + q) * 104 + kit * 32 + g * 8);
#pragma unroll
                for (int n = 0; n < 8; ++n) {
                    v8s b = *(const v8s*)(sm + W3_O + (n * 16 + q) * 104 + kit * 32 + g * 8);
                    acc3[n] = __builtin_amdgcn_mfma_f32_16x16x32_bf16(a, b, acc3[n], 0, 0, 0);
                }
            }

#pragma unroll
            for (int n = 0; n < 8; ++n) {
                int c = pc * 128 + n * 16 + q;
                float bias = hb3[p * 512 + c];
#pragma unroll
                for (int j = 0; j < 4; ++j) {
                    int r = 16 * w + 4 * g + j;
                    if (r < nr) {
                        float o = acc3[n][j] + bias;
                        size_t base = ((size_t)(p * B_ + s_rows[r])) * 256;
                        if (pc < 2) out0[base + c] = o;
                        else        out1[base + c - 256] = fminf(fmaxf(o, -6.f), 2.f);
                    }
                }
            }
        }
    }
}

extern "C" void kernel_launch(void* const* d_in, const int* in_sizes, int n_in,
                              void* d_out, int out_size, void* d_ws, size_t ws_size,
                              hipStream_t stream)
{
    (void)in_sizes; (void)n_in; (void)out_size; (void)ws_size;

    const float* mus     = (const float*)d_in[0];
    const float* logvars = (const float*)d_in[1];
    const int*   mask    = (const int*)d_in[2];   // numpy bool -> int32 per harness
    const float* hw1  = (const float*)d_in[3];
    const float* hb1  = (const float*)d_in[4];
    const float* hg1  = (const float*)d_in[5];
    const float* hbe1 = (const float*)d_in[6];
    const float* hw2  = (const float*)d_in[7];
    const float* hb2  = (const float*)d_in[8];
    const float* hg2  = (const float*)d_in[9];
    const float* hbe2 = (const float*)d_in[10];
    const float* hw3  = (const float*)d_in[11];
    const float* hb3  = (const float*)d_in[12];
    const float* gw1  = (const float*)d_in[13];
    const float* gb1  = (const float*)d_in[14];
    const float* gg1  = (const float*)d_in[15];
    const float* gbe1 = (const float*)d_in[16];
    const float* gw2  = (const float*)d_in[17];
    const float* gb2  = (const float*)d_in[18];

    float* out0 = (float*)d_out;
    float* out1 = out0 + (size_t)NP * B_ * 256;
    float* out2 = out1 + (size_t)NP * B_ * 256;

    int* counts = (int*)d_ws;                        // 16 ints
    int* lists  = counts + 16;                       // NP*B_ ints
    unsigned short* w1t = (unsigned short*)(lists + NP * B_);   // NP*65536
    unsigned short* w2t = w1t + (size_t)NP * 65536;             // NP*9216
    unsigned short* w3t = w2t + (size_t)NP * 9216;              // NP*49152

    hipMemsetAsync(d_ws, 0, 64, stream);
    k_prep<<<dim3(1024), dim3(256), 0, stream>>>(hw1, gw1, hw2, hw3, w1t, w2t, w3t);
    k_mask<<<dim3(NP * 256), dim3(256), 0, stream>>>(mask, out0, out1, out2, counts, lists);
    k_main<<<dim3(NP * 128), dim3(128), 0, stream>>>(
        mus, logvars, w1t, w2t, w3t,
        hb1, hg1, hbe1, hb2, hg2, hbe2, hb3,
        gb1, gg1, gbe1, gw2, gb2,
        counts, lists, out0, out1, out2);
}